// Round 2
// baseline (147.069 us; speedup 1.0000x reference)
//
#include <hip/hip_runtime.h>
#include <cstdint>
#include <cstddef>

// Problem constants (from reference setup_inputs):
//   batch=4, seq=4096, hidden=4096, rank=512, out_features=4096
//   M = 4*4097 = 16388 rows of all_latent
#define BATCH   4
#define SEQ     4096
#define HIDDEN  4096
#define RANK    512
#define OUTF    4096
#define SROWS   4097              // seq+1
#define MROWS   (BATCH * SROWS)   // 16388

typedef int v4i __attribute__((ext_vector_type(4)));

// ---------------------------------------------------------------------------
// Kernel 1: new_latent[b][r] = dot(new_x[b,0,:], B_weight[r,:])  (h = 4096)
// One wave per (b,r). Writes into the all_latent output region at row
// m = b*4097 + 4096.
// ---------------------------------------------------------------------------
__global__ void k_new_latent(const float* __restrict__ newx,
                             const float* __restrict__ Bw,
                             float* __restrict__ out_latent) {
    int wave = threadIdx.x >> 6;
    int lane = threadIdx.x & 63;
    int pair = blockIdx.x * 4 + wave;   // 0..2047
    int b = pair >> 9;                  // /512
    int r = pair & 511;
    const float4* x4 = (const float4*)(newx + (size_t)b * HIDDEN);
    const float4* w4 = (const float4*)(Bw + (size_t)r * HIDDEN);
    float sum = 0.f;
#pragma unroll
    for (int j = 0; j < 16; ++j) {
        float4 xv = x4[lane + 64 * j];
        float4 wv = w4[lane + 64 * j];
        sum += xv.x * wv.x + xv.y * wv.y + xv.z * wv.z + xv.w * wv.w;
    }
#pragma unroll
    for (int off = 32; off >= 1; off >>= 1)
        sum += __shfl_xor(sum, off, 64);
    if (lane == 0) {
        out_latent[(size_t)(b * SROWS + SEQ) * RANK + r] = sum;
    }
}

// ---------------------------------------------------------------------------
// Kernel 2: per-row quantization over rank=512 + copy cached rows to output.
// One wave (64 threads) per row m = b*4097+s. Each lane handles 8 floats.
//   amax = clip(max|x|, 1e-8); scale = amax/127
//   q = clip(rint(x/scale), -128, 127) -> int8 packed into ws
// ---------------------------------------------------------------------------
__global__ void k_quant(const float* __restrict__ cached,
                        float* __restrict__ out_latent,
                        int8_t* __restrict__ Qq,
                        float* __restrict__ scales) {
    int m = blockIdx.x;        // 0..16387
    int lane = threadIdx.x;    // 0..63
    int b = m / SROWS;
    int s = m - b * SROWS;
    const float* src = (s < SEQ) ? (cached + ((size_t)b * SEQ + s) * RANK)
                                 : (out_latent + (size_t)m * RANK);
    float4 v0 = ((const float4*)src)[lane];
    float4 v1 = ((const float4*)src)[64 + lane];
    float am = fmaxf(fmaxf(fmaxf(fabsf(v0.x), fabsf(v0.y)),
                           fmaxf(fabsf(v0.z), fabsf(v0.w))),
                     fmaxf(fmaxf(fabsf(v1.x), fabsf(v1.y)),
                           fmaxf(fabsf(v1.z), fabsf(v1.w))));
#pragma unroll
    for (int off = 32; off >= 1; off >>= 1)
        am = fmaxf(am, __shfl_xor(am, off, 64));
    am = fmaxf(am, 1e-8f);
    float scale = am / 127.0f;

    auto qp = [&](float x) -> uint32_t {
        float r = rintf(x / scale);          // round-half-even, matches jnp.round
        r = fminf(fmaxf(r, -128.0f), 127.0f);
        return (uint32_t)(uint8_t)(int8_t)(int)r;
    };
    uint32_t p0 = qp(v0.x) | (qp(v0.y) << 8) | (qp(v0.z) << 16) | (qp(v0.w) << 24);
    uint32_t p1 = qp(v1.x) | (qp(v1.y) << 8) | (qp(v1.z) << 16) | (qp(v1.w) << 24);
    uint32_t* qrow = (uint32_t*)(Qq + (size_t)m * RANK);
    qrow[lane] = p0;
    qrow[64 + lane] = p1;
    if (s < SEQ) {  // copy cached row into the all_latent output
        float4* dst = (float4*)(out_latent + (size_t)m * RANK);
        dst[lane] = v0;
        dst[64 + lane] = v1;
    }
    if (lane == 0) scales[m] = scale;
}

// ---------------------------------------------------------------------------
// Kernel 3: pack A_int8 (int32 storage, 4096x512) -> int8 bytes.
// ---------------------------------------------------------------------------
__global__ void k_packA(const int* __restrict__ Ai, uint8_t* __restrict__ Ap) {
    int idx = blockIdx.x * blockDim.x + threadIdx.x;   // 0..524287 (each does 4)
    int4 v = ((const int4*)Ai)[idx];
    uint32_t p = (uint32_t)(v.x & 0xff) | ((uint32_t)(v.y & 0xff) << 8) |
                 ((uint32_t)(v.z & 0xff) << 16) | ((uint32_t)(v.w & 0xff) << 24);
    ((uint32_t*)Ap)[idx] = p;
}

// ---------------------------------------------------------------------------
// Kernel 4: int8 GEMM + dequant.
//   out[m][n] = (sum_k Qq[m][k]*Ap[n][k]) * scales[m] * Ascale[n]
// m97-style: 128x128 tile, BK=64 (64 B/row in LDS), 4 waves, each wave a
// 64x64 sub-tile = 4x4 fragments of mfma_i32_16x16x64_i8.
// ---------------------------------------------------------------------------
#define BM 128
#define BN 128
#define BK 64
#define NT_N (OUTF / BN)   // 32

__launch_bounds__(256)
__global__ void k_gemm(const int8_t* __restrict__ Qq,
                       const int8_t* __restrict__ Ap,
                       const float* __restrict__ scales,
                       const float* __restrict__ Ascale,
                       float* __restrict__ out,
                       int M) {
    __shared__ __align__(16) int8_t Qs[BM * BK];   // 8 KiB
    __shared__ __align__(16) int8_t As[BN * BK];   // 8 KiB

    int tn = blockIdx.x & (NT_N - 1);
    int tm = blockIdx.x / NT_N;
    int tid = threadIdx.x;
    int lane = tid & 63;
    int wave = tid >> 6;
    int wr = wave >> 1, wc = wave & 1;

    int m0 = tm * BM;
    int n0 = tn * BN;

    v4i acc[4][4] = {};

    for (int kt = 0; kt < RANK / BK; ++kt) {
        int k0 = kt * BK;
        // Stage Q tile and A tile: 8192 B each = 512 chunks of 16 B.
        // Thread tid stages chunk idx = tid + 256*h; LDS byte = idx*16 (linear).
#pragma unroll
        for (int h = 0; h < 2; ++h) {
            int idx = tid + 256 * h;
            int row = idx >> 2;        // 64 B per row
            int g = idx & 3;           // 16 B group within row
            int grow = m0 + row; if (grow >= M) grow = M - 1;   // clamp tail
            const int8_t* srcq = Qq + (size_t)grow * RANK + k0 + g * 16;
            uint32_t ldsoff = (uint32_t)((wave * 64 + 256 * h) * 16);
            __builtin_amdgcn_global_load_lds(
                (const __attribute__((address_space(1))) uint32_t*)srcq,
                (__attribute__((address_space(3))) uint32_t*)(Qs + ldsoff),
                16, 0, 0);
            const int8_t* srca = Ap + (size_t)(n0 + row) * RANK + k0 + g * 16;
            __builtin_amdgcn_global_load_lds(
                (const __attribute__((address_space(1))) uint32_t*)srca,
                (__attribute__((address_space(3))) uint32_t*)(As + ldsoff),
                16, 0, 0);
        }
        __syncthreads();   // drains vmcnt before barrier -> LDS ready

        v4i aF[4], bF[4];
        int g = lane >> 4;
        int rl = lane & 15;
#pragma unroll
        for (int mi = 0; mi < 4; ++mi) {
            int row = wr * 64 + mi * 16 + rl;
            aF[mi] = *(const v4i*)(Qs + row * BK + g * 16);
        }
#pragma unroll
        for (int ni = 0; ni < 4; ++ni) {
            int row = wc * 64 + ni * 16 + rl;
            bF[ni] = *(const v4i*)(As + row * BK + g * 16);
        }
#pragma unroll
        for (int mi = 0; mi < 4; ++mi)
#pragma unroll
            for (int ni = 0; ni < 4; ++ni)
                acc[mi][ni] = __builtin_amdgcn_mfma_i32_16x16x64_i8(
                    aF[mi], bF[ni], acc[mi][ni], 0, 0, 0);
        __syncthreads();   // all reads done before next stage overwrites LDS
    }

    // Epilogue: dequant + store. C/D layout: col = lane&15, row = (lane>>4)*4+r.
    int gq = lane >> 4;
    int cn = lane & 15;
#pragma unroll
    for (int mi = 0; mi < 4; ++mi) {
        int mbase = m0 + wr * 64 + mi * 16 + gq * 4;
        float sm[4];
#pragma unroll
        for (int r = 0; r < 4; ++r) {
            int mm = mbase + r;
            sm[r] = (mm < M) ? scales[mm] : 0.f;
        }
#pragma unroll
        for (int ni = 0; ni < 4; ++ni) {
            int n = n0 + wc * 64 + ni * 16 + cn;
            float asc = Ascale[n];
#pragma unroll
            for (int r = 0; r < 4; ++r) {
                int mm = mbase + r;
                if (mm < M)
                    out[(size_t)mm * OUTF + n] = (float)acc[mi][ni][r] * sm[r] * asc;
            }
        }
    }
}

// ---------------------------------------------------------------------------
extern "C" void kernel_launch(void* const* d_in, const int* in_sizes, int n_in,
                              void* d_out, int out_size, void* d_ws, size_t ws_size,
                              hipStream_t stream) {
    const float* new_x  = (const float*)d_in[0];   // 4*1*4096
    const float* cached = (const float*)d_in[1];   // 4*4096*512
    const float* Bw     = (const float*)d_in[2];   // 512*4096
    const int*   Ai     = (const int*)d_in[3];     // 4096*512 (int32)
    const float* Ascale = (const float*)d_in[4];   // 4096

    float* out = (float*)d_out;                                  // 16388*4096
    float* out_latent = out + (size_t)MROWS * OUTF;              // 16388*512

    // Workspace layout
    const size_t Q_BYTES = (size_t)MROWS * RANK;                 // 8,390,656
    const size_t S_BYTES = (size_t)MROWS * sizeof(float);        // 65,552
    int8_t*  Qq     = (int8_t*)d_ws;
    float*   scales = (float*)((char*)d_ws + Q_BYTES);
    int8_t*  Ap     = (int8_t*)((char*)d_ws + Q_BYTES + S_BYTES);

    // 1. new_latent rows (writes all_latent rows s=4096)
    k_new_latent<<<512, 256, 0, stream>>>(new_x, Bw, out_latent);
    // 2. quantize all rows + copy cached rows to output
    k_quant<<<MROWS, 64, 0, stream>>>(cached, out_latent, Qq, scales);
    // 3. pack A to int8
    k_packA<<<(OUTF * RANK / 4) / 256, 256, 0, stream>>>(Ai, (uint8_t*)Ap);
    // 4. main GEMM + dequant
    int nt_m = (MROWS + BM - 1) / BM;   // 129
    k_gemm<<<nt_m * NT_N, 256, 0, stream>>>(Qq, Ap, scales, Ascale, out, MROWS);
}

// Round 3
// 135.473 us; speedup vs baseline: 1.0856x; 1.0856x over previous
//
#include <hip/hip_runtime.h>
#include <cstdint>
#include <cstddef>

#define BATCH   4
#define SEQ     4096
#define HIDDEN  4096
#define RANK    512
#define OUTF    4096
#define SROWS   4097              // seq+1
#define MROWS   (BATCH * SROWS)   // 16388

typedef int v4i __attribute__((ext_vector_type(4)));

#define AS1 __attribute__((address_space(1)))
#define AS3 __attribute__((address_space(3)))

// ---------------------------------------------------------------------------
// Kernel 1: new_latent[b][r] = dot(new_x[b,0,:], B_weight[r,:])
// ---------------------------------------------------------------------------
__global__ void k_new_latent(const float* __restrict__ newx,
                             const float* __restrict__ Bw,
                             float* __restrict__ out_latent) {
    int wave = threadIdx.x >> 6;
    int lane = threadIdx.x & 63;
    int pair = blockIdx.x * 4 + wave;   // 0..2047
    int b = pair >> 9;
    int r = pair & 511;
    const float4* x4 = (const float4*)(newx + (size_t)b * HIDDEN);
    const float4* w4 = (const float4*)(Bw + (size_t)r * HIDDEN);
    float sum = 0.f;
#pragma unroll
    for (int j = 0; j < 16; ++j) {
        float4 xv = x4[lane + 64 * j];
        float4 wv = w4[lane + 64 * j];
        sum += xv.x * wv.x + xv.y * wv.y + xv.z * wv.z + xv.w * wv.w;
    }
#pragma unroll
    for (int off = 32; off >= 1; off >>= 1)
        sum += __shfl_xor(sum, off, 64);
    if (lane == 0) {
        out_latent[(size_t)(b * SROWS + SEQ) * RANK + r] = sum;
    }
}

// ---------------------------------------------------------------------------
// Kernel 2: per-row int8 quant (rank=512) + copy cached rows to output.
// 256 threads = 4 waves, one row per wave. 4097 blocks * 4 = 16388 rows.
// ---------------------------------------------------------------------------
__global__ void k_quant(const float* __restrict__ cached,
                        float* __restrict__ out_latent,
                        int8_t* __restrict__ Qq,
                        float* __restrict__ scales) {
    int m = blockIdx.x * 4 + (threadIdx.x >> 6);   // 0..16387
    int lane = threadIdx.x & 63;
    int b = m / SROWS;
    int s = m - b * SROWS;
    const float* src = (s < SEQ) ? (cached + ((size_t)b * SEQ + s) * RANK)
                                 : (out_latent + (size_t)m * RANK);
    float4 v0 = ((const float4*)src)[lane];
    float4 v1 = ((const float4*)src)[64 + lane];
    float am = fmaxf(fmaxf(fmaxf(fabsf(v0.x), fabsf(v0.y)),
                           fmaxf(fabsf(v0.z), fabsf(v0.w))),
                     fmaxf(fmaxf(fabsf(v1.x), fabsf(v1.y)),
                           fmaxf(fabsf(v1.z), fabsf(v1.w))));
#pragma unroll
    for (int off = 32; off >= 1; off >>= 1)
        am = fmaxf(am, __shfl_xor(am, off, 64));
    am = fmaxf(am, 1e-8f);
    float scale = am / 127.0f;

    auto qp = [&](float x) -> uint32_t {
        float r = rintf(x / scale);          // round-half-even, matches jnp.round
        r = fminf(fmaxf(r, -128.0f), 127.0f);
        return (uint32_t)(uint8_t)(int8_t)(int)r;
    };
    uint32_t p0 = qp(v0.x) | (qp(v0.y) << 8) | (qp(v0.z) << 16) | (qp(v0.w) << 24);
    uint32_t p1 = qp(v1.x) | (qp(v1.y) << 8) | (qp(v1.z) << 16) | (qp(v1.w) << 24);
    uint32_t* qrow = (uint32_t*)(Qq + (size_t)m * RANK);
    qrow[lane] = p0;
    qrow[64 + lane] = p1;
    if (s < SEQ) {
        float4* dst = (float4*)(out_latent + (size_t)m * RANK);
        dst[lane] = v0;
        dst[64 + lane] = v1;
    }
    if (lane == 0) scales[m] = scale;
}

// ---------------------------------------------------------------------------
// Kernel 3: pack A_int8 (int32 storage, 4096x512) -> int8 bytes.
// ---------------------------------------------------------------------------
__global__ void k_packA(const int* __restrict__ Ai, uint8_t* __restrict__ Ap) {
    int idx = blockIdx.x * blockDim.x + threadIdx.x;
    int4 v = ((const int4*)Ai)[idx];
    uint32_t p = (uint32_t)(v.x & 0xff) | ((uint32_t)(v.y & 0xff) << 8) |
                 ((uint32_t)(v.z & 0xff) << 16) | ((uint32_t)(v.w & 0xff) << 24);
    ((uint32_t*)Ap)[idx] = p;
}

// ---------------------------------------------------------------------------
// Kernel 4: int8 GEMM + dequant, double-buffered LDS with counted vmcnt.
//   out[m][n] = (sum_k Qq[m][k]*Ap[n][k]) * scales[m] * Ascale[n]
// 128x128 tile, BK=64, 8 K-steps, 4 waves each owning a 64x64 sub-tile.
// Per K-step each thread issues 4 global_load_lds (16B). The wait before
// compute is vmcnt(4): the 4 newest (next tile's prefetch) stay in flight.
// ---------------------------------------------------------------------------
#define BM 128
#define BN 128
#define BK 64
#define NT_N (OUTF / BN)   // 32
#define NKT  (RANK / BK)   // 8

__launch_bounds__(256, 4)
__global__ void k_gemm(const int8_t* __restrict__ Qq,
                       const int8_t* __restrict__ Ap,
                       const float* __restrict__ scales,
                       const float* __restrict__ Ascale,
                       float* __restrict__ out,
                       int M) {
    __shared__ __align__(16) int8_t Qs[2][BM * BK];   // 2 x 8 KiB
    __shared__ __align__(16) int8_t As[2][BN * BK];   // 2 x 8 KiB

    // XCD-bijective blockIdx swizzle (gridDim.x = 4128, 4128 % 8 == 0):
    // each XCD gets a contiguous stripe of tm-major blocks -> Q-tile L2 reuse.
    int per = gridDim.x >> 3;
    int bid = blockIdx.x;
    int swz = (bid & 7) * per + (bid >> 3);
    int tn = swz & (NT_N - 1);
    int tm = swz / NT_N;

    int tid = threadIdx.x;
    int lane = tid & 63;
    int wave = tid >> 6;
    int wr = wave >> 1, wc = wave & 1;

    int m0 = tm * BM;
    int n0 = tn * BN;

    // Staging addresses: chunk idx = tid + 256*h (h=0,1), row = idx>>2,
    // 16B group = idx&3. LDS is linear: chunk idx at byte idx*16.
    int row0 = tid >> 2;            // 0..63
    int row1 = row0 + 64;           // 64..127
    int gb = (tid & 3) * 16;
    int grow0 = m0 + row0; if (grow0 >= M) grow0 = M - 1;
    int grow1 = m0 + row1; if (grow1 >= M) grow1 = M - 1;
    const int8_t* q0 = Qq + (size_t)grow0 * RANK + gb;
    const int8_t* q1 = Qq + (size_t)grow1 * RANK + gb;
    const int8_t* a0 = Ap + (size_t)(n0 + row0) * RANK + gb;
    const int8_t* a1 = Ap + (size_t)(n0 + row1) * RANK + gb;
    uint32_t w16 = (uint32_t)(wave * 1024);   // wave-uniform LDS byte base

#define STAGE(bufi, kt) do {                                                  \
    int off_ = (kt) * BK;                                                     \
    __builtin_amdgcn_global_load_lds((const AS1 uint32_t*)(q0 + off_),        \
        (AS3 uint32_t*)(&Qs[bufi][0] + w16), 16, 0, 0);                       \
    __builtin_amdgcn_global_load_lds((const AS1 uint32_t*)(q1 + off_),        \
        (AS3 uint32_t*)(&Qs[bufi][0] + w16 + 4096), 16, 0, 0);                \
    __builtin_amdgcn_global_load_lds((const AS1 uint32_t*)(a0 + off_),        \
        (AS3 uint32_t*)(&As[bufi][0] + w16), 16, 0, 0);                       \
    __builtin_amdgcn_global_load_lds((const AS1 uint32_t*)(a1 + off_),        \
        (AS3 uint32_t*)(&As[bufi][0] + w16 + 4096), 16, 0, 0);                \
  } while (0)

    v4i acc[4][4] = {};
    int g = lane >> 4;
    int rl = lane & 15;

    STAGE(0, 0);
#pragma unroll
    for (int kt = 0; kt < NKT; ++kt) {
        int cb = kt & 1;
        if (kt < NKT - 1) {
            STAGE(cb ^ 1, kt + 1);
            asm volatile("s_waitcnt vmcnt(4)" ::: "memory");
        } else {
            asm volatile("s_waitcnt vmcnt(0)" ::: "memory");
        }
        __builtin_amdgcn_s_barrier();   // tile kt fully in LDS for all waves

        v4i aF[4], bF[4];
#pragma unroll
        for (int mi = 0; mi < 4; ++mi) {
            int row = wr * 64 + mi * 16 + rl;
            aF[mi] = *(const v4i*)(&Qs[cb][0] + row * BK + g * 16);
        }
#pragma unroll
        for (int ni = 0; ni < 4; ++ni) {
            int row = wc * 64 + ni * 16 + rl;
            bF[ni] = *(const v4i*)(&As[cb][0] + row * BK + g * 16);
        }
#pragma unroll
        for (int mi = 0; mi < 4; ++mi)
#pragma unroll
            for (int ni = 0; ni < 4; ++ni)
                acc[mi][ni] = __builtin_amdgcn_mfma_i32_16x16x64_i8(
                    aF[mi], bF[ni], acc[mi][ni], 0, 0, 0);

        __builtin_amdgcn_s_barrier();   // reads done; next iter may overwrite cb^... buf
    }
#undef STAGE

    // Epilogue: dequant + store. C/D layout: col = lane&15, row = (lane>>4)*4+r.
    int gq = lane >> 4;
    int cn = lane & 15;
#pragma unroll
    for (int mi = 0; mi < 4; ++mi) {
        int mbase = m0 + wr * 64 + mi * 16 + gq * 4;
        float sm[4];
#pragma unroll
        for (int r = 0; r < 4; ++r) {
            int mm = mbase + r;
            sm[r] = (mm < M) ? scales[mm] : 0.f;
        }
#pragma unroll
        for (int ni = 0; ni < 4; ++ni) {
            int n = n0 + wc * 64 + ni * 16 + cn;
            float asc = Ascale[n];
#pragma unroll
            for (int r = 0; r < 4; ++r) {
                int mm = mbase + r;
                if (mm < M)
                    out[(size_t)mm * OUTF + n] = (float)acc[mi][ni][r] * sm[r] * asc;
            }
        }
    }
}

// ---------------------------------------------------------------------------
extern "C" void kernel_launch(void* const* d_in, const int* in_sizes, int n_in,
                              void* d_out, int out_size, void* d_ws, size_t ws_size,
                              hipStream_t stream) {
    const float* new_x  = (const float*)d_in[0];
    const float* cached = (const float*)d_in[1];
    const float* Bw     = (const float*)d_in[2];
    const int*   Ai     = (const int*)d_in[3];
    const float* Ascale = (const float*)d_in[4];

    float* out = (float*)d_out;
    float* out_latent = out + (size_t)MROWS * OUTF;

    const size_t Q_BYTES = (size_t)MROWS * RANK;
    const size_t S_BYTES = (size_t)MROWS * sizeof(float);
    int8_t*  Qq     = (int8_t*)d_ws;
    float*   scales = (float*)((char*)d_ws + Q_BYTES);
    int8_t*  Ap     = (int8_t*)((char*)d_ws + Q_BYTES + S_BYTES);

    k_new_latent<<<512, 256, 0, stream>>>(new_x, Bw, out_latent);
    k_quant<<<SROWS, 256, 0, stream>>>(cached, out_latent, Qq, scales);
    k_packA<<<(OUTF * RANK / 4) / 256, 256, 0, stream>>>(Ai, (uint8_t*)Ap);
    int nt_m = (MROWS + BM - 1) / BM;   // 129
    k_gemm<<<nt_m * NT_N, 256, 0, stream>>>(Qq, Ap, scales, Ascale, out, MROWS);
}